// Round 20
// baseline (849.871 us; speedup 1.0000x reference)
//
#include <hip/hip_runtime.h>
#include <hip/hip_fp16.h>
#include <cmath>

// DHT: out[n,c,a,r] = sum over px (x,y) of feat[n,c,y,x],
//   r = rint((x-128)*cos(a deg) + (y-128)*sin(a deg)) + 361  (r in [180,542])
// feat[4,128,256,256] f32 -> out[4,128,180,723] f32.
//
// Locked-in findings:
//  R1-R4: LDS f32 atomicAdd ~per-lane serial -> never on hot path.
//  R5/R18: program-ordered DS RMW race-free iff lanes' bins distinct PER
//    INSTRUCTION; source-level read-hoisting across lane-overlapping writes
//    races. R10: exec-masked DS poison. R16: occupancy can't add port BW.
//  R12/R15/R17: SQ_LDS_BANK_CONFLICT = PORT-BYTE tax (prop. to RMW bytes,
//    invariant to addresses & instruction width). R17 (846us): f16 accum,
//    4img/b64. R19 (813us): dual-angle no-alias chains, small ILP gain.
//  Budget at R19: port 0.74M + byte-tax 0.54M + ~0.67M == ~3.6cyc/DS-instr
//    (m134: every DS width shows ~+4cyc/instr over port bytes).
//  R20: halve DS INSTRUCTIONS at constant bytes: 8 images per b128 RMW
//    (h8 = 8xf16). 184K -> 92K instr/CU, predicted -0.35M cyc.
//    512-thr blocks (8 waves), 4 scan-quarters, dual-angle chains kept.

#define NA 180
#define NR 723
#define HW 65536
#define NC 512
#define ROW_W 368       // bins rl = r-RBASE in [4,366]
#define ROW_PAD 368
#define RBASE 176
#define NWIN 32         // 8-px windows along the scan axis
#define NCP 8           // wave copies per block

__device__ __forceinline__ bool is_phase2(int a) { return a >= 46 && a <= 134; }

// 8 images packed per bin: a={img0,1} b={img2,3} c={img4,5} d={img6,7}
struct __align__(16) h8 { __half2 a, b, c, d; };

// ---------------------------------------------------------------------------
// win[a][w][fast] u32 = base bin at scan=8w (bits 0..15), step bits 16..22.
// Phase-1 (a in [0,45]u[135,179]): fast=x, scan=y. Phase-2 (a in [46,134]):
// fast=y, scan=x (sign flips at 90). fp64 non-fused + rint == np.round
// (validated R1-R19).
// ---------------------------------------------------------------------------
__global__ __launch_bounds__(256) void dht_win(unsigned int* __restrict__ win) {
    const int lane = threadIdx.x;
    const int w = blockIdx.x;
    const int a = blockIdx.y;
    const double theta = (double)a * (M_PI / 180.0);
    const double c = cos(theta), s = sin(theta);
    const bool p2 = is_phase2(a);
    int prev = 0;
    unsigned int word = 0;
    #pragma unroll
    for (int i = 0; i < 8; ++i) {
        const int k = w * 8 + i;
        const int x = p2 ? k : lane;
        const int y = p2 ? lane : k;
        const double rho = __dadd_rn(__dmul_rn((double)(x - 128), c),
                                     __dmul_rn((double)(y - 128), s));
        int r = (int)rint(rho) + 361;
        r = min(max(r, 0), NR - 1);
        if (i == 0) word = (unsigned int)r;
        else if (r != prev) word |= (1u << (15 + i));
        prev = r;
    }
    win[((size_t)a * NWIN + w) * 256 + lane] = word;
}

__global__ __launch_bounds__(256) void zero_out(float4* __restrict__ o, int n4) {
    const int i = blockIdx.x * 256 + threadIdx.x;
    if (i < n4) o[i] = make_float4(0.f, 0.f, 0.f, 0.f);
}

// Single-angle walk (tail chunk). Strict per-visit read->add->write order;
// lanes 2 cols apart -> bins >= 1.414 apart per instruction -> race-free.
template <int SGN>
__device__ __forceinline__ void walk_one(const uint4 wq,
                                         const __half2 (&pP)[8][4],
                                         const __half2 (&pQ)[8][4],
                                         const __half2 (&pR)[8][4],
                                         const __half2 (&pS)[8][4],
                                         h8* __restrict__ rp) {
    #pragma unroll
    for (int j = 0; j < 4; ++j) {
        const unsigned int wrd = (&wq.x)[j];
        int bin = (int)(wrd & 0xffffu) - RBASE;
        #pragma unroll
        for (int k = 0; k < 8; ++k) {
            if (k) bin += SGN * (int)((wrd >> (15 + k)) & 1u);
            h8 v = rp[bin];
            v.a = __hadd2(v.a, pP[k][j]);
            v.b = __hadd2(v.b, pQ[k][j]);
            v.c = __hadd2(v.c, pR[k][j]);
            v.d = __hadd2(v.d, pS[k][j]);
            rp[bin] = v;
        }
    }
}

// Dual-angle walk into DISTINCT __shared__ objects (provable no-alias ->
// the two chains' reads batch per latency window). Per-chain order = R17.
template <int SGN0, int SGN1>
__device__ __forceinline__ void walk_dual(const uint4 wq0, const uint4 wq1,
                                          const __half2 (&pP)[8][4],
                                          const __half2 (&pQ)[8][4],
                                          const __half2 (&pR)[8][4],
                                          const __half2 (&pS)[8][4],
                                          h8* __restrict__ rpA,
                                          h8* __restrict__ rpB) {
    #pragma unroll
    for (int j = 0; j < 4; ++j) {
        const unsigned int w0 = (&wq0.x)[j];
        const unsigned int w1 = (&wq1.x)[j];
        int b0 = (int)(w0 & 0xffffu) - RBASE;
        int b1 = (int)(w1 & 0xffffu) - RBASE;
        #pragma unroll
        for (int k = 0; k < 8; ++k) {
            if (k) {
                b0 += SGN0 * (int)((w0 >> (15 + k)) & 1u);
                b1 += SGN1 * (int)((w1 >> (15 + k)) & 1u);
            }
            h8 vA = rpA[b0];
            h8 vB = rpB[b1];
            vA.a = __hadd2(vA.a, pP[k][j]);
            vA.b = __hadd2(vA.b, pQ[k][j]);
            vA.c = __hadd2(vA.c, pR[k][j]);
            vA.d = __hadd2(vA.d, pS[k][j]);
            vB.a = __hadd2(vB.a, pP[k][j]);
            vB.b = __hadd2(vB.b, pQ[k][j]);
            vB.c = __hadd2(vB.c, pR[k][j]);
            vB.d = __hadd2(vB.d, pS[k][j]);
            rpA[b0] = vA;
            rpB[b1] = vB;
        }
    }
}

// ---------------------------------------------------------------------------
// Block = (image-oct, phase, scan-quarter). 512 thr = 8 waves; wave wv owns
// scan window w = 8z+wv (8 scan lines); lane owns fast columns
// {2l, 2l+1, 2l+128, 2l+129} (j=0..3). px = 128 __half2 (8 scan x 4 col x
// 8 img f16), loaded+converted ONCE, reused across all angles of the phase.
// rowsA/rowsB[8 waves][ROW_PAD] h8 = 47.1 KB each -> 94 KB, 1 block/CU.
// ---------------------------------------------------------------------------
__global__ __launch_bounds__(512, 2) void dht_main(const float* __restrict__ feat,
                                                   const unsigned int* __restrict__ win,
                                                   float* __restrict__ out) {
    __shared__ h8 rowsA[NCP * ROW_PAD];   // angle cb+0 of each chunk
    __shared__ h8 rowsB[NCP * ROW_PAD];   // angle cb+1 of each chunk
    const int t = threadIdx.x;
    const int wv = t >> 6;               // 0..7
    const int l = t & 63;
    const int oct = blockIdx.x;          // 0..63
    const int phase = blockIdx.y;
    const int z = blockIdx.z;            // scan quarter 0..3
    const int w = 8 * z + wv;            // scan window 0..31
    const int k0 = 8 * w;                // scan offset

    const float* const fp[8] = {
        feat + (size_t)(8 * oct + 0) * HW, feat + (size_t)(8 * oct + 1) * HW,
        feat + (size_t)(8 * oct + 2) * HW, feat + (size_t)(8 * oct + 3) * HW,
        feat + (size_t)(8 * oct + 4) * HW, feat + (size_t)(8 * oct + 5) * HW,
        feat + (size_t)(8 * oct + 6) * HW, feat + (size_t)(8 * oct + 7) * HW };
    float* const op[8] = {
        out + (size_t)(8 * oct + 0) * (NA * NR), out + (size_t)(8 * oct + 1) * (NA * NR),
        out + (size_t)(8 * oct + 2) * (NA * NR), out + (size_t)(8 * oct + 3) * (NA * NR),
        out + (size_t)(8 * oct + 4) * (NA * NR), out + (size_t)(8 * oct + 5) * (NA * NR),
        out + (size_t)(8 * oct + 6) * (NA * NR), out + (size_t)(8 * oct + 7) * (NA * NR) };

    const int fj0 = 2 * l;        // cols j=0,1
    const int fj2 = 2 * l + 128;  // cols j=2,3

    // ---- load persistent px tile: 8 scan x 4 col x 8 img, f16 packed ----
    // pP = {img0,1}, pQ = {img2,3}, pR = {img4,5}, pS = {img6,7}
    __half2 pP[8][4], pQ[8][4], pR[8][4], pS[8][4];
    if (phase == 0) {
        #pragma unroll
        for (int k = 0; k < 8; ++k) {
            const int ro = (k0 + k) << 8;
            float2 u0[8], u2[8];
            #pragma unroll
            for (int im = 0; im < 8; ++im) {
                u0[im] = *(const float2*)(fp[im] + ro + fj0);
                u2[im] = *(const float2*)(fp[im] + ro + fj2);
            }
            pP[k][0] = __floats2half2_rn(u0[0].x, u0[1].x);
            pQ[k][0] = __floats2half2_rn(u0[2].x, u0[3].x);
            pR[k][0] = __floats2half2_rn(u0[4].x, u0[5].x);
            pS[k][0] = __floats2half2_rn(u0[6].x, u0[7].x);
            pP[k][1] = __floats2half2_rn(u0[0].y, u0[1].y);
            pQ[k][1] = __floats2half2_rn(u0[2].y, u0[3].y);
            pR[k][1] = __floats2half2_rn(u0[4].y, u0[5].y);
            pS[k][1] = __floats2half2_rn(u0[6].y, u0[7].y);
            pP[k][2] = __floats2half2_rn(u2[0].x, u2[1].x);
            pQ[k][2] = __floats2half2_rn(u2[2].x, u2[3].x);
            pR[k][2] = __floats2half2_rn(u2[4].x, u2[5].x);
            pS[k][2] = __floats2half2_rn(u2[6].x, u2[7].x);
            pP[k][3] = __floats2half2_rn(u2[0].y, u2[1].y);
            pQ[k][3] = __floats2half2_rn(u2[2].y, u2[3].y);
            pR[k][3] = __floats2half2_rn(u2[4].y, u2[5].y);
            pS[k][3] = __floats2half2_rn(u2[6].y, u2[7].y);
        }
    } else {
        #pragma unroll
        for (int j = 0; j < 4; ++j) {
            const int fr = (j < 2) ? (fj0 + j) : (fj2 + (j - 2));
            const int ro = fr << 8;
            float4 qa[8], qb[8];
            #pragma unroll
            for (int im = 0; im < 8; ++im) {
                qa[im] = *(const float4*)(fp[im] + ro + k0);
                qb[im] = *(const float4*)(fp[im] + ro + k0 + 4);
            }
            #pragma unroll
            for (int k = 0; k < 4; ++k) {
                const float v0 = (&qa[0].x)[k], v1 = (&qa[1].x)[k];
                const float v2 = (&qa[2].x)[k], v3 = (&qa[3].x)[k];
                const float v4 = (&qa[4].x)[k], v5 = (&qa[5].x)[k];
                const float v6 = (&qa[6].x)[k], v7 = (&qa[7].x)[k];
                pP[k][j] = __floats2half2_rn(v0, v1);
                pQ[k][j] = __floats2half2_rn(v2, v3);
                pR[k][j] = __floats2half2_rn(v4, v5);
                pS[k][j] = __floats2half2_rn(v6, v7);
            }
            #pragma unroll
            for (int k = 0; k < 4; ++k) {
                const float v0 = (&qb[0].x)[k], v1 = (&qb[1].x)[k];
                const float v2 = (&qb[2].x)[k], v3 = (&qb[3].x)[k];
                const float v4 = (&qb[4].x)[k], v5 = (&qb[5].x)[k];
                const float v6 = (&qb[6].x)[k], v7 = (&qb[7].x)[k];
                pP[k + 4][j] = __floats2half2_rn(v0, v1);
                pQ[k + 4][j] = __floats2half2_rn(v2, v3);
                pR[k + 4][j] = __floats2half2_rn(v4, v5);
                pS[k + 4][j] = __floats2half2_rn(v6, v7);
            }
        }
    }

    const int nAng = phase ? 89 : 91;   // both odd: dual chunks + one tail
    for (int cb = 0; cb < nAng; cb += 2) {
        const int cn = min(2, nAng - cb);
        {   // zero both copies (bit pattern 0 == f16 zero); h8 = one float4
            float4* zA = (float4*)rowsA;
            float4* zB = (float4*)rowsB;
            for (int i = t; i < NCP * ROW_PAD; i += 512) {
                zA[i] = make_float4(0.f, 0.f, 0.f, 0.f);
                zB[i] = make_float4(0.f, 0.f, 0.f, 0.f);
            }
        }
        __syncthreads();

        const int a0 = phase ? (46 + cb) : (cb <= 45 ? cb : cb + 89);
        h8* __restrict__ rpA = rowsA + wv * ROW_PAD;
        if (cn == 2) {
            const int ax1 = cb + 1;
            const int a1 = phase ? (46 + ax1) : (ax1 <= 45 ? ax1 : ax1 + 89);
            const unsigned int* wr0 = win + ((size_t)a0 * NWIN + w) * 256;
            const unsigned int* wr1 = win + ((size_t)a1 * NWIN + w) * 256;
            const uint2 p00 = *(const uint2*)(wr0 + fj0);
            const uint2 p01 = *(const uint2*)(wr0 + fj2);
            const uint2 p10 = *(const uint2*)(wr1 + fj0);
            const uint2 p11 = *(const uint2*)(wr1 + fj2);
            uint4 wq0; wq0.x = p00.x; wq0.y = p00.y; wq0.z = p01.x; wq0.w = p01.y;
            uint4 wq1; wq1.x = p10.x; wq1.y = p10.y; wq1.z = p11.x; wq1.w = p11.y;
            h8* __restrict__ rpB = rowsB + wv * ROW_PAD;
            if (!phase || a1 <= 90)
                walk_dual<+1, +1>(wq0, wq1, pP, pQ, pR, pS, rpA, rpB);
            else if (a0 > 90)
                walk_dual<-1, -1>(wq0, wq1, pP, pQ, pR, pS, rpA, rpB);
            else
                walk_dual<+1, -1>(wq0, wq1, pP, pQ, pR, pS, rpA, rpB);
        } else {
            const unsigned int* wr0 = win + ((size_t)a0 * NWIN + w) * 256;
            const uint2 p00 = *(const uint2*)(wr0 + fj0);
            const uint2 p01 = *(const uint2*)(wr0 + fj2);
            uint4 wq0; wq0.x = p00.x; wq0.y = p00.y; wq0.z = p01.x; wq0.w = p01.y;
            if (phase && a0 > 90) walk_one<-1>(wq0, pP, pQ, pR, pS, rpA);
            else                  walk_one<+1>(wq0, pP, pQ, pR, pS, rpA);
        }
        __syncthreads();

        // flush: sum 8 wave copies in f32; lanes iterate rl contiguously ->
        // contiguous global atomics, 8 per element (one per image). Exactly-4
        // commutative contributions per out element (4 quarters).
        for (int i = t; i < cn * ROW_W; i += 512) {
            const int al = i / ROW_W;
            const int rl = i - al * ROW_W;
            const h8* __restrict__ src = al ? rowsB : rowsA;
            float s0 = 0.f, s1 = 0.f, s2 = 0.f, s3 = 0.f;
            float s4 = 0.f, s5 = 0.f, s6 = 0.f, s7 = 0.f;
            #pragma unroll
            for (int c2 = 0; c2 < NCP; ++c2) {
                const h8 v = src[c2 * ROW_PAD + rl];
                s0 += __low2float(v.a); s1 += __high2float(v.a);
                s2 += __low2float(v.b); s3 += __high2float(v.b);
                s4 += __low2float(v.c); s5 += __high2float(v.c);
                s6 += __low2float(v.d); s7 += __high2float(v.d);
            }
            const int aidx = cb + al;
            const int a = phase ? (46 + aidx) : (aidx <= 45 ? aidx : aidx + 89);
            const size_t o = (size_t)a * NR + (RBASE + rl);
            unsafeAtomicAdd(op[0] + o, s0);
            unsafeAtomicAdd(op[1] + o, s1);
            unsafeAtomicAdd(op[2] + o, s2);
            unsafeAtomicAdd(op[3] + o, s3);
            unsafeAtomicAdd(op[4] + o, s4);
            unsafeAtomicAdd(op[5] + o, s5);
            unsafeAtomicAdd(op[6] + o, s6);
            unsafeAtomicAdd(op[7] + o, s7);
        }
        __syncthreads();
    }
}

extern "C" void kernel_launch(void* const* d_in, const int* in_sizes, int n_in,
                              void* d_out, int out_size, void* d_ws, size_t ws_size,
                              hipStream_t stream) {
    const float* feat = (const float*)d_in[0];
    float* out = (float*)d_out;
    unsigned int* win = (unsigned int*)d_ws;

    const size_t win_bytes = (size_t)NA * NWIN * 256 * sizeof(unsigned int); // 5.9MB
    if (ws_size < win_bytes) return;

    const int n4 = out_size / 4;   // out_size = 512*180*723, divisible by 4
    hipLaunchKernelGGL(zero_out, dim3((n4 + 255) / 256), dim3(256), 0, stream,
                       (float4*)out, n4);
    hipLaunchKernelGGL(dht_win, dim3(NWIN, NA), dim3(256), 0, stream, win);
    hipLaunchKernelGGL(dht_main, dim3(NC / 8, 2, 4), dim3(512), 0, stream,
                       feat, win, out);
}